// Round 2
// baseline (1044.003 us; speedup 1.0000x reference)
//
#include <hip/hip_runtime.h>

// Problem constants (fixed by the reference module).
constexpr int B = 4, C = 256, H = 256, W = 512;
constexpr int MAXLOAD = 100, FS = 14;
constexpr int NROI = B * MAXLOAD;            // 400
constexpr int HB = B * H;                    // 1024 (flattened b*h rows)
constexpr int FS2 = FS * FS;                 // 196
constexpr int MAIN = NROI * C * FS2;         // 20,070,400 elements of out[0]
constexpr int MAIN_BLOCKS = C * NROI;        // 102,400 — one block per (c,n)
constexpr int NXCD = 8;
constexpr int CHUNK = MAIN_BLOCKS / NXCD;    // 12,800 (bijective: MAIN_BLOCKS%8==0)
constexpr int SEGW = 514;                    // padded LDS row (max x-span is 512)

__global__ __launch_bounds__(256) void pooler_kernel(
    const float* __restrict__ feats,   // (B,C,H,W) fp32
    const float* __restrict__ rois,    // (B*MAXLOAD, 4) fp32: x0,y0,x1,y1
    float* __restrict__ out)           // (NROI,C,FS,FS) fp32 ++ val_bind(NROI)
{
    // double-buffered: [buf][row j: {fy0:y0, fy0:y1, fy1:y0, fy1:y1}][x]
    __shared__ float buf[2][4][SEGW];  // 16.4 KB -> 8 blocks/CU by LDS

    int bid = blockIdx.x;
    if (bid >= MAIN_BLOCKS) {
        // val_bind tail: repeat(arange(B), MAXLOAD), written as float
        int t = (bid - MAIN_BLOCKS) * 256 + threadIdx.x;
        if (t < NROI)
            __builtin_nontemporal_store((float)(t / MAXLOAD), &out[MAIN + t]);
        return;
    }

    // XCD-chunked, c-major: concurrent blocks on one XCD share a channel ->
    // that channel's 4 image slices (~2 MB touched) stay L2-resident, so
    // overlapping ROIs hit L2 and each HBM line is fetched once.
    int wg = (bid % NXCD) * CHUNK + bid / NXCD;
    int c  = wg / NROI;
    int n  = wg - c * NROI;
    int vb = n / MAXLOAD;

    float4 roi = reinterpret_cast<const float4*>(rois)[n];
    float scalex = roi.z - roi.x;
    float scaley = roi.w - roi.y;
    float biasx  = roi.x;
    float biasy  = roi.y + (float)vb * 1024.0f;  // image_height = 1024

    // x-segment bounds: same fp expressions as the per-lane compute (px is
    // monotone in fx since scalex>0), so every lane's x0/x1 lands in [x_start,x_end].
    float px_lo = fminf(fmaxf(((0.0f  * (1.0f/13.0f) * scalex + biasx) * 0.25f)
                              * (512.0f/511.0f) - 0.5f, 0.0f), (float)(W - 1));
    float px_hi = fminf(fmaxf(((13.0f * (1.0f/13.0f) * scalex + biasx) * 0.25f)
                              * (512.0f/511.0f) - 0.5f, 0.0f), (float)(W - 1));
    int x_start = (int)floorf(px_lo);
    int x_end   = min((int)floorf(px_hi) + 1, W - 1);
    int seg     = x_end - x_start + 1;           // 2..512, uniform per block

    int cHW      = c * (H * W);
    int out_base = (n * C + c) * FS2;

    int tid  = threadIdx.x;
    int j    = tid >> 6;     // wave id 0..3 -> which of the 4 rows to stage
    int lane = tid & 63;

    // stage rows for fy = 2q, 2q+1 into buf[qb]: one row per wave,
    // lane-strided -> 64 consecutive floats (256 B) per instruction.
    auto stage = [&](int q, int qb) {
        int fy = 2 * q + (j >> 1);
        float gy = ((float)fy * (1.0f/13.0f) * scaley + biasy) * 0.25f;
        float py = fminf(fmaxf(gy * (1024.0f/1023.0f) - 0.5f, 0.0f), (float)(HB - 1));
        int y0 = (int)floorf(py);
        int y  = (j & 1) ? min(y0 + 1, HB - 1) : y0;
        // feats viewed as (C, HB, W); row may cross image boundary like reference
        int base = ((y >> 8) * (C * H) + (y & (H - 1))) * W + cHW + x_start;
        for (int k = lane; k < seg; k += 64)
            buf[qb][j][k] = feats[base + k];
    };

    stage(0, 0);
    __syncthreads();

    for (int p = 0; p < 7; ++p) {
        if (p < 6) stage(p + 1, (p + 1) & 1);   // prefetch next phase (other buffer)

        if (tid < 28) {                          // 2 fy x 14 fx outputs
            int half = tid / 14;                 // 0 -> fy=2p, 1 -> fy=2p+1
            int fx   = tid - half * 14;
            int fy   = 2 * p + half;

            float gx  = ((float)fx * (1.0f/13.0f) * scalex + biasx) * 0.25f;
            float gyv = ((float)fy * (1.0f/13.0f) * scaley + biasy) * 0.25f;
            float px = fminf(fmaxf(gx  * (512.0f/511.0f)  - 0.5f, 0.0f), (float)(W - 1));
            float py = fminf(fmaxf(gyv * (1024.0f/1023.0f) - 0.5f, 0.0f), (float)(HB - 1));

            float x0f = floorf(px), y0f = floorf(py);
            float wx = px - x0f,  wy = py - y0f;
            int i0 = (int)x0f - x_start;
            int i1 = min((int)x0f + 1, W - 1) - x_start;

            const float* r0 = buf[p & 1][half * 2 + 0];
            const float* r1 = buf[p & 1][half * 2 + 1];
            float f00 = r0[i0], f01 = r0[i1];
            float f10 = r1[i0], f11 = r1[i1];

            float v0 = f00 + wx * (f01 - f00);
            float v1 = f10 + wx * (f11 - f10);
            float res = v0 + wy * (v1 - v0);
            __builtin_nontemporal_store(res, &out[out_base + fy * FS + fx]);
        }
        __syncthreads();  // stage(p+1) done AND compute(p) done before reuse
    }
}

extern "C" void kernel_launch(void* const* d_in, const int* in_sizes, int n_in,
                              void* d_out, int out_size, void* d_ws, size_t ws_size,
                              hipStream_t stream) {
    const float* feats = (const float*)d_in[0];
    const float* rois  = (const float*)d_in[1];
    float* out = (float*)d_out;

    int tail_blocks = (NROI + 255) / 256;                 // 2
    pooler_kernel<<<MAIN_BLOCKS + tail_blocks, 256, 0, stream>>>(feats, rois, out);
}

// Round 3
// 702.200 us; speedup vs baseline: 1.4868x; 1.4868x over previous
//
#include <hip/hip_runtime.h>

// Problem constants (fixed by the reference module).
constexpr int B = 4, C = 256, H = 256, W = 512;
constexpr int MAXLOAD = 100, FS = 14;
constexpr int NROI = B * MAXLOAD;            // 400
constexpr int HB = B * H;                    // 1024 (flattened b*h rows)
constexpr int FS2 = FS * FS;                 // 196
constexpr int MAIN = NROI * C * FS2;         // 20,070,400 elements of out[0]
constexpr int TOTAL = MAIN + NROI;           // + val_bind tail
constexpr int MAIN_BLOCKS = MAIN / 256;      // 78,400 (exact)
constexpr int NXCD = 8;
constexpr int CHUNK = MAIN_BLOCKS / NXCD;    // 9,800 (bijective: 78400 % 8 == 0)

__global__ __launch_bounds__(256) void pooler_kernel(
    const float* __restrict__ feats,   // (B,C,H,W) fp32
    const float* __restrict__ rois,    // (B*MAXLOAD, 4) fp32: x0,y0,x1,y1
    float* __restrict__ out)           // (NROI,C,FS,FS) fp32 ++ val_bind(NROI)
{
    int bid = blockIdx.x;

    if (bid >= MAIN_BLOCKS) {
        // val_bind tail: repeat(arange(B), MAXLOAD), written as float
        int t = (bid - MAIN_BLOCKS) * 256 + threadIdx.x;
        if (t < NROI)
            __builtin_nontemporal_store((float)(t / MAXLOAD), &out[MAIN + t]);
        return;
    }

    // XCD-chunk swizzle + c-major enumeration (best measured variant, R1):
    // each XCD owns a contiguous 1/8 of (c,n) space -> its private L2 stays
    // on a ~32-channel slice; cross-ROI overlap hits L2. Bijective.
    int wg = (bid % NXCD) * CHUNK + bid / NXCD;
    int e  = wg * 256 + threadIdx.x;

    // e = (c*NROI + n)*FS2 + pos
    int pos = e % FS2;
    int qq  = e / FS2;
    int n   = qq % NROI;
    int c   = qq / NROI;
    int fx  = pos % FS;
    int fy  = pos / FS;
    int vb  = n / MAXLOAD;   // batch of this roi

    float4 roi = reinterpret_cast<const float4*>(rois)[n];
    float scalex = roi.z - roi.x;
    float scaley = roi.w - roi.y;
    float biasx  = roi.x;
    float biasy  = roi.y + (float)vb * 1024.0f;  // image_height = 1024

    // grid coords (dscale = 4)
    float gridx = ((float)fx * (1.0f / 13.0f) * scalex + biasx) * 0.25f;
    float gridy = ((float)fy * (1.0f / 13.0f) * scaley + biasy) * 0.25f;

    // Algebraic simplification of reference's normalize->denormalize round
    // trip (verified passing, absmax 0.0156 within tolerance).
    float px = gridx * (512.0f / 511.0f) - 0.5f;
    float py = gridy * (1024.0f / 1023.0f) - 0.5f;
    px = fminf(fmaxf(px, 0.0f), (float)(W - 1));
    py = fminf(fmaxf(py, 0.0f), (float)(HB - 1));

    float x0f = floorf(px), y0f = floorf(py);
    float wx = px - x0f, wy = py - y0f;
    int x0 = (int)x0f, y0 = (int)y0f;
    int y1 = min(y0 + 1, HB - 1);

    // feats viewed as (C, HB, W): flat = ((y>>8)*C*H + (y&255))*W + c*H*W + x
    int cb  = c * (H * W);
    int ro0 = ((y0 >> 8) * (C * H) + (y0 & (H - 1))) * W + cb;
    int ro1 = ((y1 >> 8) * (C * H) + (y1 & (H - 1))) * W + cb;

    // One float2 per row instead of two scalar loads: (f00,f01) share a cache
    // line; a single dwordx2 makes the TA process that line ONCE. xb clamp
    // keeps the pair in-row; x1 = min(x0+1, W-1) is always the .y element.
    int xb = min(x0, W - 2);
    bool hi = (x0 != xb);            // true only when x0 == W-1
    float2 v0 = *reinterpret_cast<const float2*>(&feats[ro0 + xb]);
    float2 v1 = *reinterpret_cast<const float2*>(&feats[ro1 + xb]);
    float f00 = hi ? v0.y : v0.x;
    float f01 = v0.y;
    float f10 = hi ? v1.y : v1.x;
    float f11 = v1.y;

    float r0 = f00 + wx * (f01 - f00);
    float r1 = f10 + wx * (f11 - f10);
    float res = r0 + wy * (r1 - r0);

    int out_idx = (n * C + c) * FS2 + pos;
    __builtin_nontemporal_store(res, &out[out_idx]);
}

extern "C" void kernel_launch(void* const* d_in, const int* in_sizes, int n_in,
                              void* d_out, int out_size, void* d_ws, size_t ws_size,
                              hipStream_t stream) {
    const float* feats = (const float*)d_in[0];
    const float* rois  = (const float*)d_in[1];
    float* out = (float*)d_out;

    int tail_blocks = (NROI + 255) / 256;     // 2
    pooler_kernel<<<MAIN_BLOCKS + tail_blocks, 256, 0, stream>>>(feats, rois, out);
}